// Round 12
// baseline (51.903 us; speedup 1.0000x reference)
//
#include <hip/hip_runtime.h>

// Implicit-GEMM MFMA v6 — 32x32x16 MFMA, hh-pair packed into N; PDG=1.
// Conv3d(3->16,k3,valid)+bias, /2, MaxPool3d(2), GlobalAvgPool, +bias, channel-sum.
// out[n] = (1/(2*14415)) * sum_{c,windows} max_window(conv_c) + sum_c(cb_c/2 + bias_c)
//
// Block = (ph, pd, n). LDS xt[w][k], k=ci*16+drel*4+h (48 real, 16 pad), bf16,
// 16B-slot XOR swizzle by (w&7). Wave wid: dd=wid>>1, mtile=wid&1 (w rows 32).
// B[k][col] frags (col<16: hh=0 ch=col; col>=16: hh=1 ch=col-16) precomputed in ws.
// kw via 3 accumulating MFMAs, A rows shifted by kw. C: col=lane&31,
// row=(reg&3)+8*(reg>>2)+4*(lane>>5) [m74/m101]. ww-max in-lane reg pairs,
// hh-max via shfl_xor(16), dd-max via pool LDS.

using f32x16 = __attribute__((ext_vector_type(16))) float;
using bf16x8 = __attribute__((ext_vector_type(8))) short;
using s16x4  = __attribute__((ext_vector_type(4))) short;
using s16x8  = __attribute__((ext_vector_type(8))) short;

__device__ inline unsigned short f2bf(float f) {
  unsigned int u = __float_as_uint(f);
  unsigned int r = 0x7fffu + ((u >> 16) & 1u);   // RNE for finite inputs
  return (unsigned short)((u + r) >> 16);
}

#define WS_FRAG_OFF 16384   // u32 units: frags at ws + 64 KB (needs ws >= 83 KB)

// ---- prep: B fragments for (dd, kchunk=ci, kw, lane). 1152 x 16B.
__global__ void prep_bfrags(const float* __restrict__ wgt, float* __restrict__ ws)
{
  int idx = blockIdx.x*256 + threadIdx.x;   // 0..1279, guard 1152
  if (idx >= 1152) return;
  short* fb = (short*)((unsigned int*)ws + WS_FRAG_OFF);
  int l = idx & 63, rest = idx >> 6;        // rest 0..17
  int kw = rest % 3, kc = (rest/3) % 3, dd = rest/9;
  int col = l & 31, half = l >> 5;
  int ch = col & 15, hh = col >> 4;
  short f[8];
  #pragma unroll
  for (int j = 0; j < 8; ++j) {
    int kloc = half*8 + j;                  // 0..15
    int drel = kloc >> 2, h = kloc & 3;
    int kd = drel - dd, kh = h - hh;
    bool ok = (kd >= 0) && (kd < 3) && (kh >= 0) && (kh < 3);
    float v = ok ? wgt[ch*81 + kc*27 + kd*9 + kh*3 + kw] : 0.f;
    f[j] = (short)f2bf(v);
  }
  bf16x8 q = { f[0], f[1], f[2], f[3], f[4], f[5], f[6], f[7] };
  *reinterpret_cast<bf16x8*>(&fb[idx*8]) = q;
}

__global__ __launch_bounds__(256, 3) void conv_mfma_kernel(
    const float* __restrict__ x, const float* __restrict__ ws_in,
    float* __restrict__ ws)
{
  __shared__ __align__(16) unsigned short xt[66*64];   // 8448 B, swizzled
  __shared__ float pool[2*32*16];                      // 4096 B: [dd][pw][ch]
  __shared__ float wsum[4];

  const int tid = threadIdx.x;
  const int ph  = blockIdx.x;       // 0..30
  const int pd  = blockIdx.y;       // 0..14
  const int n   = blockIdx.z;       // 0..31
  const int l   = tid & 63;
  const int wid = tid >> 6;
  const int dd = wid >> 1, mtile = wid & 1;
  const int half = l >> 5;

  const int w  = tid & 63;
  const int kq = tid >> 6;

  // ---- issue this wave's 9 B-frag loads early (L2-hot, independent of staging)
  const short* fb = (const short*)((const unsigned int*)ws_in + WS_FRAG_OFF);
  bf16x8 bfr[3][3];
  #pragma unroll
  for (int kc = 0; kc < 3; ++kc)
    #pragma unroll
    for (int kw = 0; kw < 3; ++kw)
      bfr[kc][kw] = *reinterpret_cast<const bf16x8*>(
          &fb[(((dd*3 + kc)*3 + kw)*64 + l)*8]);

  // ---- zero never-written pads: k-slots 6,7 per row (16B each, XOR-bijective)
  // + rows 64,65 (A reads reach row 65).
  {
    s16x8 z = {0,0,0,0,0,0,0,0};
    if (kq < 2)
      *reinterpret_cast<s16x8*>(&xt[w*64 + ((48 + kq*8) ^ ((w & 7) << 3))]) = z;
    else if (w < 8)
      *reinterpret_cast<s16x8*>(&xt[(64 + (kq - 2))*64 + w*8]) = z;
  }

  // ---- stage x: xt[w][k] = bf16(x[ci][D0+d][H0+h][w]), k=ci*16+drel*4+h
  const float* xn = x + (size_t)n*(3*32*64*64);
  const int D0 = 2*pd, H0 = 2*ph;
  {
    short va[12];
    #pragma unroll
    for (int t = 0; t < 12; ++t) {
      int k = kq*12 + t;
      int ci = k >> 4, d = (k >> 2) & 3, hq = k & 3;
      va[t] = (short)f2bf(xn[((size_t)(ci*32 + D0 + d)*64 + (H0 + hq))*64 + w]);
    }
    #pragma unroll
    for (int p = 0; p < 3; ++p) {
      int off = (kq*12 + p*4) ^ ((w & 7) << 3);   // elem units; 16B-slot swizzle
      s16x4 v = { va[p*4], va[p*4+1], va[p*4+2], va[p*4+3] };
      *reinterpret_cast<s16x4*>(&xt[w*64 + off]) = v;
    }
  }
  __syncthreads();

  // ---- main loop: 9 x (ds_read_b128 + mfma_32x32x16), no barriers
  const int rowbase = mtile*32 + (l & 31);
  f32x16 acc = {0.f,0.f,0.f,0.f,0.f,0.f,0.f,0.f,0.f,0.f,0.f,0.f,0.f,0.f,0.f,0.f};
  #pragma unroll
  for (int kc = 0; kc < 3; ++kc) {
    #pragma unroll
    for (int kw = 0; kw < 3; ++kw) {
      int row = rowbase + kw;
      int off = ((kc*2 + half)*8) ^ ((row & 7) << 3);
      bf16x8 af = *reinterpret_cast<const bf16x8*>(&xt[row*64 + off]);
      acc = __builtin_amdgcn_mfma_f32_32x32x16_bf16(af, bfr[kc][kw], acc, 0, 0, 0);
    }
  }

  // ---- epilogue: ww-max (in-lane reg pairs), hh-max (shfl_xor 16), pool[dd]
  float pv[8];
  #pragma unroll
  for (int j = 0; j < 8; ++j) pv[j] = fmaxf(acc[2*j], acc[2*j + 1]);
  #pragma unroll
  for (int j = 0; j < 8; ++j) pv[j] = fmaxf(pv[j], __shfl_xor(pv[j], 16, 64));
  if (!(l & 16)) {
    int ch = l & 15;
    #pragma unroll
    for (int j = 0; j < 8; ++j) {
      int pwl = 4*(j >> 1) + (j & 1) + 2*half;    // 0..15 within mtile
      pool[(dd*32 + mtile*16 + pwl)*16 + ch] = pv[j];
    }
  }
  __syncthreads();

  // ---- dd-max + sum over (pw<=30, ch)
  float S = 0.f;
  #pragma unroll
  for (int r = 0; r < 2; ++r) {
    int i = tid + r*256;               // [pw][ch] flat, 512 entries per dd
    if (i < 496)                       // pw < 31
      S += fmaxf(pool[i], pool[512 + i]);
  }
  #pragma unroll
  for (int off = 32; off > 0; off >>= 1) S += __shfl_down(S, off, 64);
  if ((tid & 63) == 0) wsum[tid >> 6] = S;
  __syncthreads();
  if (tid == 0)
    ws[n*512 + pd*31 + ph] = wsum[0] + wsum[1] + wsum[2] + wsum[3];
}

// ---- finalize: one block per n, 64 lanes stride the 465 partials.
__global__ void finalize_kernel(const float* __restrict__ ws,
                                const float* __restrict__ cb,
                                const float* __restrict__ bias,
                                float* __restrict__ out)
{
  const int n = blockIdx.x, l = threadIdx.x;
  float t = 0.f;
  #pragma unroll
  for (int r = 0; r < 8; ++r) {
    int s = l + r*64;
    if (s < 465) t += ws[n*512 + s];
  }
  #pragma unroll
  for (int off = 32; off > 0; off >>= 1) t += __shfl_down(t, off, 64);
  if (l == 0) {
    float C = 0.f;
    #pragma unroll
    for (int c = 0; c < 16; ++c) C += cb[c]*0.5f + bias[c];
    out[n] = t * (1.0f/(2.0f*14415.0f)) + C;
  }
}

extern "C" void kernel_launch(void* const* d_in, const int* in_sizes, int n_in,
                              void* d_out, int out_size, void* d_ws, size_t ws_size,
                              hipStream_t stream) {
  (void)in_sizes; (void)n_in; (void)out_size; (void)ws_size;
  const float* x    = (const float*)d_in[0];
  const float* wgt  = (const float*)d_in[1];
  const float* cb   = (const float*)d_in[2];
  const float* bias = (const float*)d_in[3];
  float* out = (float*)d_out;
  float* ws  = (float*)d_ws;     // 64 KB partials + 18.4 KB frags

  prep_bfrags<<<5, 256, 0, stream>>>(wgt, ws);
  dim3 grid(31, 15, 32);         // (ph, pd, n) = 14880 blocks
  conv_mfma_kernel<<<grid, 256, 0, stream>>>(x, ws, ws);
  finalize_kernel<<<32, 64, 0, stream>>>(ws, cb, bias, out);
}

// Round 14
// 46.853 us; speedup vs baseline: 1.1078x; 1.1078x over previous
//
#include <hip/hip_runtime.h>

// Implicit-GEMM MFMA v7b — v7 with pool stride fix (p*1024 + dd*512).
// Conv3d(3->16,k3,valid)+bias, /2, MaxPool3d(2), GlobalAvgPool, +bias, channel-sum.
// out[n] = (1/(2*14415)) * sum_{c,windows} max_window(conv_c) + sum_c(cb_c/2 + bias_c)
//
// Block = (ph, pdg, n), pd = 2*pdg + p, p in {0,1} (pdg=7 ragged: p=0 only).
// LDS xt[p][w][k], k=ci*16+drel*4+h (48 real), bf16, 16B-slot XOR swizzle (w&7).
// Stage 6 unique d-slices once; overlap slices (s=2,3) written to both buffers.
// Wave wid: dd=wid>>1, mtile=wid&1. B[k][col] frags precomputed (ws), col<16:
// hh=0, col>=16: hh=1. kw via 3 accumulating MFMAs, A rows shifted by kw.
// C: col=lane&31, row=(reg&3)+8*(reg>>2)+4*(lane>>5).

using f32x16 = __attribute__((ext_vector_type(16))) float;
using bf16x8 = __attribute__((ext_vector_type(8))) short;
using s16x4  = __attribute__((ext_vector_type(4))) short;

__device__ inline unsigned short f2bf(float f) {
  unsigned int u = __float_as_uint(f);
  unsigned int r = 0x7fffu + ((u >> 16) & 1u);   // RNE for finite inputs
  return (unsigned short)((u + r) >> 16);
}

#define WS_FRAG_OFF 16384   // u32 units: frags at ws + 64 KB (needs ws >= 83 KB)

// ---- prep: B fragments for (dd, kchunk=ci, kw, lane). 1152 x 16B.
__global__ void prep_bfrags(const float* __restrict__ wgt, float* __restrict__ ws)
{
  int idx = blockIdx.x*256 + threadIdx.x;   // 0..1279, guard 1152
  if (idx >= 1152) return;
  short* fb = (short*)((unsigned int*)ws + WS_FRAG_OFF);
  int l = idx & 63, rest = idx >> 6;        // rest 0..17
  int kw = rest % 3, kc = (rest/3) % 3, dd = rest/9;
  int col = l & 31, half = l >> 5;
  int ch = col & 15, hh = col >> 4;
  short f[8];
  #pragma unroll
  for (int j = 0; j < 8; ++j) {
    int kloc = half*8 + j;                  // 0..15
    int drel = kloc >> 2, h = kloc & 3;
    int kd = drel - dd, kh = h - hh;
    bool ok = (kd >= 0) && (kd < 3) && (kh >= 0) && (kh < 3);
    float v = ok ? wgt[ch*81 + kc*27 + kd*9 + kh*3 + kw] : 0.f;
    f[j] = (short)f2bf(v);
  }
  bf16x8 q = { f[0], f[1], f[2], f[3], f[4], f[5], f[6], f[7] };
  *reinterpret_cast<bf16x8*>(&fb[idx*8]) = q;
}

__global__ __launch_bounds__(256, 3) void conv_mfma_kernel(
    const float* __restrict__ x, const float* __restrict__ ws_in,
    float* __restrict__ ws)
{
  __shared__ __align__(16) unsigned short xt[2][66*64];  // 16,896 B, swizzled
  __shared__ float pool[2*2*32*16];                      // 8,192 B: [p][dd][pw][ch]
  __shared__ float wsum[4];

  const int tid = threadIdx.x;
  const int ph  = blockIdx.x;       // 0..30
  const int pdg = blockIdx.y;       // 0..7 -> pd = 2*pdg + p
  const int n   = blockIdx.z;       // 0..31
  const int l   = tid & 63;
  const int wid = tid >> 6;
  const int dd = wid >> 1, mtile = wid & 1;
  const int half = l >> 5;
  const int w  = tid & 63;
  const int kq = tid >> 6;

  // ---- issue this wave's 9 B-frag loads early (independent of staging)
  const short* fb = (const short*)((const unsigned int*)ws_in + WS_FRAG_OFF);
  bf16x8 bfr[3][3];
  #pragma unroll
  for (int kc = 0; kc < 3; ++kc)
    #pragma unroll
    for (int kw = 0; kw < 3; ++kw)
      bfr[kc][kw] = *reinterpret_cast<const bf16x8*>(
          &fb[(((dd*3 + kc)*3 + kw)*64 + l)*8]);

  // ---- stage 6 unique d-slices: group g=(ci,s), s=0..5, abs d=4*pdg+s.
  // drel = s - 2p in [0,4): s<4 -> buf0, s>=2 -> buf1.
  const float* xn = x + (size_t)n*(3*32*64*64);
  const int D0 = 4*pdg, H0 = 2*ph;
  #pragma unroll
  for (int j = 0; j < 5; ++j) {
    int g = kq + 4*j;                 // wave-uniform
    if (g >= 18) break;
    int ci = g / 6, s = g - 6*ci;
    int d  = D0 + s; d = (d < 32) ? d : 31;   // clamp (ragged pdg=7; excluded)
    const float* xp = xn + (size_t)(ci*32 + d)*4096 + H0*64 + w;
    short va[4];
    #pragma unroll
    for (int h = 0; h < 4; ++h) va[h] = (short)f2bf(xp[h*64]);
    s16x4 v = { va[0], va[1], va[2], va[3] };
    if (s < 4) {
      int off = (ci*16 + s*4) ^ ((w & 7) << 3);
      *reinterpret_cast<s16x4*>(&xt[0][w*64 + off]) = v;
    }
    if (s >= 2) {
      int off = (ci*16 + (s - 2)*4) ^ ((w & 7) << 3);
      *reinterpret_cast<s16x4*>(&xt[1][w*64 + off]) = v;
    }
  }
  __syncthreads();

  // ---- 2 pds: 9 x (ds_read_b128 + mfma_32x32x16) each, epilogue to pool[p]
  const int rowbase = mtile*32 + (l & 31);
  #pragma unroll 1
  for (int p = 0; p < 2; ++p) {
    f32x16 acc = {0.f,0.f,0.f,0.f,0.f,0.f,0.f,0.f,0.f,0.f,0.f,0.f,0.f,0.f,0.f,0.f};
    #pragma unroll
    for (int kc = 0; kc < 3; ++kc) {
      #pragma unroll
      for (int kw = 0; kw < 3; ++kw) {
        int row = rowbase + kw;
        int off = ((kc*2 + half)*8) ^ ((row & 7) << 3);
        bf16x8 af = *reinterpret_cast<const bf16x8*>(&xt[p][row*64 + off]);
        acc = __builtin_amdgcn_mfma_f32_32x32x16_bf16(af, bfr[kc][kw], acc, 0, 0, 0);
      }
    }
    // ww-max (in-lane reg pairs), hh-max (shfl_xor 16) -> pool[p][dd]
    float pv[8];
    #pragma unroll
    for (int jj = 0; jj < 8; ++jj) pv[jj] = fmaxf(acc[2*jj], acc[2*jj + 1]);
    #pragma unroll
    for (int jj = 0; jj < 8; ++jj) pv[jj] = fmaxf(pv[jj], __shfl_xor(pv[jj], 16, 64));
    if (!(l & 16)) {
      int ch = l & 15;
      #pragma unroll
      for (int jj = 0; jj < 8; ++jj) {
        int pwl = 4*(jj >> 1) + (jj & 1) + 2*half;    // 0..15 within mtile
        pool[p*1024 + dd*512 + (mtile*16 + pwl)*16 + ch] = pv[jj];
      }
    }
  }
  __syncthreads();

  // ---- dd-max + sum over (p valid, pw<=30, ch)
  const int pmax = (pdg == 7) ? 1 : 2;
  float S = 0.f;
  #pragma unroll 1
  for (int p = 0; p < pmax; ++p) {
    #pragma unroll
    for (int r = 0; r < 2; ++r) {
      int i = tid + r*256;             // [pw][ch] flat, 512 per dd
      if (i < 496)                     // pw < 31
        S += fmaxf(pool[p*1024 + i], pool[p*1024 + 512 + i]);
    }
  }
  #pragma unroll
  for (int off = 32; off > 0; off >>= 1) S += __shfl_down(S, off, 64);
  if ((tid & 63) == 0) wsum[tid >> 6] = S;
  __syncthreads();
  if (tid == 0)
    ws[n*256 + pdg*31 + ph] = wsum[0] + wsum[1] + wsum[2] + wsum[3];
}

// ---- finalize: one block per n, 64 lanes stride the 248 partials.
__global__ void finalize_kernel(const float* __restrict__ ws,
                                const float* __restrict__ cb,
                                const float* __restrict__ bias,
                                float* __restrict__ out)
{
  const int n = blockIdx.x, l = threadIdx.x;
  float t = 0.f;
  #pragma unroll
  for (int r = 0; r < 4; ++r) {
    int s = l + r*64;
    if (s < 248) t += ws[n*256 + s];
  }
  #pragma unroll
  for (int off = 32; off > 0; off >>= 1) t += __shfl_down(t, off, 64);
  if (l == 0) {
    float C = 0.f;
    #pragma unroll
    for (int c = 0; c < 16; ++c) C += cb[c]*0.5f + bias[c];
    out[n] = t * (1.0f/(2.0f*14415.0f)) + C;
  }
}

extern "C" void kernel_launch(void* const* d_in, const int* in_sizes, int n_in,
                              void* d_out, int out_size, void* d_ws, size_t ws_size,
                              hipStream_t stream) {
  (void)in_sizes; (void)n_in; (void)out_size; (void)ws_size;
  const float* x    = (const float*)d_in[0];
  const float* wgt  = (const float*)d_in[1];
  const float* cb   = (const float*)d_in[2];
  const float* bias = (const float*)d_in[3];
  float* out = (float*)d_out;
  float* ws  = (float*)d_ws;     // partials 32 KB @0; frags 18.4 KB @64 KB

  prep_bfrags<<<5, 256, 0, stream>>>(wgt, ws);
  dim3 grid(31, 8, 32);          // (ph, pdg, n) = 7936 blocks
  conv_mfma_kernel<<<grid, 256, 0, stream>>>(x, ws, ws);
  finalize_kernel<<<32, 64, 0, stream>>>(ws, cb, bias, out);
}